// Round 7
// baseline (5280.714 us; speedup 1.0000x reference)
//
#include <hip/hip_runtime.h>
#include <math.h>

#define B_ 16
#define N_ 2048
#define M_ 2048
#define ITERS_ 100
#define RCH_ 64
#define NCH_ (N_ / RCH_)            // 32 chunks
// (1/eps)*log2(e), eps = 0.1
#define SCALE_ 14.426950408889634f
// u16 fixed-point C: Chat = c16/65535
#define KQ_ (SCALE_ / 65535.0f)

typedef float f4 __attribute__((ext_vector_type(4)));
typedef unsigned short u16x8 __attribute__((ext_vector_type(8)));

static __device__ __forceinline__ f4 exp2v(f4 x) {
  return f4{exp2f(x.x), exp2f(x.y), exp2f(x.z), exp2f(x.w)};
}
static __device__ __forceinline__ float hsum(f4 x) {
  return (x.x + x.y) + (x.z + x.w);
}

// One fused Sinkhorn iteration, factorized exp-domain, F-update fused as a
// per-block prologue:
//   prologue: S[m] = sum_s psum[s][b][m]  (psum is RAW col sums of g*t)
//             F[m] = q'[m]/S[m];  lF[m] = log2(F[m]);  Finv = S/q' kept for
//             this thread's 8 output columns.
//   hot loop: e = 2^(lF[m] - KQ*c16)  ( = F[m]*t[n,m] ), rs = sum_m e,
//             g = p'/rs,  sr[m] += g*e
//   epilogue: cross-wave LDS reduce, psum_out = sr_tot * Finv  (raw again)
// V=0: first iter (F==1, reads fp32 C, writes u16 T, no prologue/divide)
// V=1: hot iters (reads u16 T)
// V=2: last iter (reads fp32 C exact, writes g_out)
// Block (b,s): rows [s*64,s*64+64); 4 waves x 16 rows; lane owns cols
// {k*512 + 8*lane + j : k=0..3, j=0..7} (16B T loads, 2x16B C loads).
template <int V>
__global__ __launch_bounds__(256, 2) void sink_iter(
    const float* __restrict__ C, unsigned short* __restrict__ T,
    const float* __restrict__ p, const float* __restrict__ q,
    float* __restrict__ psum, float* __restrict__ g_out) {
  __shared__ float lds[4][M_];  // 32 KB
  const int tid = threadIdx.x;
  const int lane = tid & 63, w = tid >> 6;
  const int bid = blockIdx.x;
  const int b = bid >> 5, s = bid & (NCH_ - 1);

  f4 lF[8];
  f4 Finv0 = f4{1.f, 1.f, 1.f, 1.f}, Finv1 = f4{1.f, 1.f, 1.f, 1.f};
  if (V == 0) {
#pragma unroll
    for (int k = 0; k < 8; k++) lF[k] = f4{0.f, 0.f, 0.f, 0.f};
  } else {
    f4 S[8];
#pragma unroll
    for (int k = 0; k < 8; k++) S[k] = f4{0.f, 0.f, 0.f, 0.f};
#pragma unroll 4
    for (int s2 = 0; s2 < NCH_; s2++) {
      const f4* P = (const f4*)(psum + (size_t)(s2 * B_ + b) * M_);
#pragma unroll
      for (int k = 0; k < 4; k++) {
        S[2 * k] += P[k * 128 + 2 * lane];
        S[2 * k + 1] += P[k * 128 + 2 * lane + 1];
      }
    }
    const f4* Q = (const f4*)(q + (size_t)b * M_);
#pragma unroll
    for (int k = 0; k < 4; k++) {
      f4 qa = Q[k * 128 + 2 * lane] + 1e-8f;
      f4 qb = Q[k * 128 + 2 * lane + 1] + 1e-8f;
      f4 ra = qa / S[2 * k];
      f4 rb = qb / S[2 * k + 1];
      lF[2 * k] = f4{log2f(ra.x), log2f(ra.y), log2f(ra.z), log2f(ra.w)};
      lF[2 * k + 1] = f4{log2f(rb.x), log2f(rb.y), log2f(rb.z), log2f(rb.w)};
      if (k == w) {  // this thread's epilogue columns
        Finv0 = S[2 * k] / qa;
        Finv1 = S[2 * k + 1] / qb;
      }
    }
  }

  f4 sr[8];
#pragma unroll
  for (int k = 0; k < 8; k++) sr[k] = f4{0.f, 0.f, 0.f, 0.f};

  const int row0 = s * RCH_ + w * 16;
  const float* prow = p + (size_t)b * N_ + row0;

#pragma unroll 2
  for (int i = 0; i < 16; i++) {
    const size_t roff = ((size_t)b * N_ + row0 + i) * (size_t)M_;
    f4 e[8];
    float rs = 0.f;
    if (V == 1) {
      const u16x8* Tr = (const u16x8*)(T + roff);
#pragma unroll
      for (int k = 0; k < 4; k++) {
        u16x8 t = Tr[k * 64 + lane];
        f4 x0 = f4{(float)t[0], (float)t[1], (float)t[2], (float)t[3]};
        f4 x1 = f4{(float)t[4], (float)t[5], (float)t[6], (float)t[7]};
        x0 = lF[2 * k] - KQ_ * x0;
        x1 = lF[2 * k + 1] - KQ_ * x1;
        e[2 * k] = exp2v(x0);
        e[2 * k + 1] = exp2v(x1);
        rs += hsum(e[2 * k]) + hsum(e[2 * k + 1]);
      }
    } else {
      const f4* Cr = (const f4*)(C + roff);
#pragma unroll
      for (int k = 0; k < 4; k++) {
        f4 c0 = Cr[k * 128 + 2 * lane];
        f4 c1 = Cr[k * 128 + 2 * lane + 1];
        if (V == 0) {  // persist u16 T for hot iterations
          u16x8 o;
          o[0] = (unsigned short)rintf(c0.x * 65535.f);
          o[1] = (unsigned short)rintf(c0.y * 65535.f);
          o[2] = (unsigned short)rintf(c0.z * 65535.f);
          o[3] = (unsigned short)rintf(c0.w * 65535.f);
          o[4] = (unsigned short)rintf(c1.x * 65535.f);
          o[5] = (unsigned short)rintf(c1.y * 65535.f);
          o[6] = (unsigned short)rintf(c1.z * 65535.f);
          o[7] = (unsigned short)rintf(c1.w * 65535.f);
          ((u16x8*)(T + roff))[k * 64 + lane] = o;
        }
        f4 x0 = lF[2 * k] - SCALE_ * c0;
        f4 x1 = lF[2 * k + 1] - SCALE_ * c1;
        e[2 * k] = exp2v(x0);
        e[2 * k + 1] = exp2v(x1);
        rs += hsum(e[2 * k]) + hsum(e[2 * k + 1]);
      }
    }
#pragma unroll
    for (int o = 32; o; o >>= 1) rs += __shfl_xor(rs, o, 64);
    float g = (prow[i] + 1e-8f) / rs;
    if (V == 2 && lane == 0) g_out[(size_t)b * N_ + row0 + i] = g;
#pragma unroll
    for (int k = 0; k < 8; k++) sr[k] += e[k] * g;
  }

  // cross-wave column reduction -> psum (raw colsums: divide out F)
#pragma unroll
  for (int k = 0; k < 4; k++) {
    *(f4*)&lds[w][k * 512 + 8 * lane] = sr[2 * k];
    *(f4*)&lds[w][k * 512 + 8 * lane + 4] = sr[2 * k + 1];
  }
  __syncthreads();
  {
    int base = w * 512 + 8 * lane;
    f4 a0 = *(const f4*)&lds[0][base] + *(const f4*)&lds[1][base] +
            *(const f4*)&lds[2][base] + *(const f4*)&lds[3][base];
    f4 a1 = *(const f4*)&lds[0][base + 4] + *(const f4*)&lds[1][base + 4] +
            *(const f4*)&lds[2][base + 4] + *(const f4*)&lds[3][base + 4];
    a0 *= Finv0;
    a1 *= Finv1;
    float* po = &psum[(size_t)(s * B_ + b) * M_ + base];
    *(f4*)po = a0;
    *(f4*)(po + 4) = a1;
  }
}

// Final F: F[m] = q'[m] / sum_s psum[s][b][m]
__global__ __launch_bounds__(256) void fin_F(
    const float* __restrict__ psum, const float* __restrict__ q,
    float* __restrict__ F) {
  int gid = blockIdx.x * 256 + threadIdx.x;  // f4 granule over B_*M_/4
  int b = gid >> 9;
  int mg = gid & 511;
  f4 S = f4{0.f, 0.f, 0.f, 0.f};
  const f4* P = (const f4*)psum;
#pragma unroll 8
  for (int s = 0; s < NCH_; s++)
    S += P[(size_t)(s * B_ + b) * (M_ / 4) + mg];
  f4 qq = ((const f4*)q)[gid] + 1e-8f;
  ((f4*)F)[gid] = qq / S;
}

// pi = g[n] * F[m] * 2^(-SCALE_*C)  (exact fp32 C)
__global__ __launch_bounds__(256) void pi_kernel(
    const float* __restrict__ C, const float* __restrict__ g_arr,
    const float* __restrict__ F_arr, float* __restrict__ out) {
  int bid = blockIdx.x;
  int tid = threadIdx.x;
  int b = bid >> 11;
  float gg = g_arr[bid];
  const f4* Cr = (const f4*)(C + (size_t)bid * M_);
  const f4* Fr = (const f4*)(F_arr + (size_t)b * M_);
  f4* Or = (f4*)(out + (size_t)bid * M_);
#pragma unroll
  for (int k = 0; k < 2; k++) {
    int i = tid + (k << 8);
    f4 c = __builtin_nontemporal_load(&Cr[i]);
    f4 f = Fr[i];
    f4 r;
    r.x = gg * f.x * exp2f(-SCALE_ * c.x);
    r.y = gg * f.y * exp2f(-SCALE_ * c.y);
    r.z = gg * f.z * exp2f(-SCALE_ * c.z);
    r.w = gg * f.w * exp2f(-SCALE_ * c.w);
    __builtin_nontemporal_store(r, &Or[i]);
  }
}

extern "C" void kernel_launch(void* const* d_in, const int* in_sizes, int n_in,
                              void* d_out, int out_size, void* d_ws, size_t ws_size,
                              hipStream_t stream) {
  const float* p = (const float*)d_in[0];
  const float* q = (const float*)d_in[1];
  const float* C = (const float*)d_in[2];
  float* out = (float*)d_out;

  const size_t Telems = (size_t)B_ * N_ * M_;   // 67.1M u16 = 134 MB
  const size_t psz = (size_t)NCH_ * B_ * M_;    // 1,048,576 floats = 4 MB
  const size_t gsz = (size_t)B_ * N_;
  const size_t fsz = (size_t)B_ * M_;
  const size_t need_all =
      Telems * sizeof(unsigned short) + (psz + gsz + fsz) * sizeof(float);

  unsigned short* T;
  float *psum, *g_arr, *F_arr;
  if (ws_size >= need_all) {
    T = (unsigned short*)d_ws;
    psum = (float*)(T + Telems);
    g_arr = psum + psz;
    F_arr = g_arr + gsz;
  } else {
    // g,F in ws (256 KB); T in d_out front (134 MB), psum in d_out tail (4 MB).
    // psum is (re)written by V0 before any prologue reads it; T written by V0;
    // pi_kernel finally rewrites all of d_out reading only C/g/F -> safe,
    // deterministic (no state carried across calls).
    g_arr = (float*)d_ws;
    F_arr = g_arr + gsz;
    T = (unsigned short*)d_out;
    psum = out + ((size_t)out_size - psz);
  }

  sink_iter<0><<<B_ * NCH_, 256, 0, stream>>>(C, T, p, q, psum, g_arr);
  for (int t = 1; t < ITERS_ - 1; ++t)
    sink_iter<1><<<B_ * NCH_, 256, 0, stream>>>(C, T, p, q, psum, g_arr);
  sink_iter<2><<<B_ * NCH_, 256, 0, stream>>>(C, T, p, q, psum, g_arr);
  fin_F<<<B_ * M_ / 1024, 256, 0, stream>>>(psum, q, F_arr);
  pi_kernel<<<B_ * N_, 256, 0, stream>>>(C, g_arr, F_arr, out);
}